// Round 21
// baseline (88.868 us; speedup 1.0000x reference)
//
#include <hip/hip_runtime.h>

using f32x4 = __attribute__((ext_vector_type(4))) float;
using h8v   = __attribute__((ext_vector_type(8))) _Float16;
using h4v   = __attribute__((ext_vector_type(4))) _Float16;
using s8v   = __attribute__((ext_vector_type(8))) short;

#define MFMAH(a, b, c)   __builtin_amdgcn_mfma_f32_16x16x32_f16((a), (b), (c), 0, 0, 0)
#define MFMAH16(a, b, c) __builtin_amdgcn_mfma_f32_16x16x16f16((a), (b), (c), 0, 0, 0)

typedef __attribute__((address_space(3))) unsigned int lds_uint;
typedef const __attribute__((address_space(1))) unsigned int glb_uint;
__device__ inline void gload16(void* l, const void* g) {
    __builtin_amdgcn_global_load_lds((glb_uint*)g, (lds_uint*)l, 16, 0, 0);
}

// native 2^x (v_exp_f32); large-negative input flushes to 0
__device__ inline float exp2_fast(float x) {
    float r;
    asm("v_exp_f32 %0, %1" : "=v"(r) : "v"(x));
    return r;
}

// ---------------------------------------------------------------------------
// Fused fp32 -> fp16 conversion for x, w_qkv, w_out. 8 elems/thread.
// ---------------------------------------------------------------------------
__global__ __launch_bounds__(256) void conv_all(const float* __restrict__ x,
                                                const float* __restrict__ wq,
                                                const float* __restrict__ wo,
                                                _Float16* __restrict__ xh,
                                                _Float16* __restrict__ wqh,
                                                _Float16* __restrict__ woh) {
    const int i = blockIdx.x * blockDim.x + threadIdx.x;
    const float* src;
    _Float16* dst;
    int off;
    if (i < 442368)      { src = x;  dst = xh;  off = i; }
    else if (i < 663552) { src = wq; dst = wqh; off = i - 442368; }
    else                 { src = wo; dst = woh; off = i - 663552; }
    const float4 a = *(const float4*)(src + (size_t)off * 8);
    const float4 b = *(const float4*)(src + (size_t)off * 8 + 4);
    h8v h;
    h[0] = (_Float16)a.x; h[1] = (_Float16)a.y; h[2] = (_Float16)a.z; h[3] = (_Float16)a.w;
    h[4] = (_Float16)b.x; h[5] = (_Float16)b.y; h[6] = (_Float16)b.z; h[7] = (_Float16)b.w;
    *(h8v*)(dst + (size_t)off * 8) = h;
}

// ---------------------------------------------------------------------------
// Stage 1: qkv = x @ w_qkv^T  (fp16), BK=64 DOUBLE-BUFFERED counted pipeline:
// per K-step {vmcnt(0) [loads had a full compute phase in flight]; barrier;
// issue next-tile loads; 32 MFMA} -> 12 barriers (vs 24), load latency hidden
// under compute. XCD swizzle (648 = 8*81). Q,K cols (bx<12) -> qkv;
// V cols (bx>=12) written DIRECTLY TRANSPOSED into vt (vtrans fused).
// ---------------------------------------------------------------------------
__global__ __launch_bounds__(256) void gemm_qkv_f16(const _Float16* __restrict__ A,
                                                    const _Float16* __restrict__ B,
                                                    _Float16* __restrict__ C,
                                                    _Float16* __restrict__ vt) {
    constexpr int LD = 768, LDC = 2304;
    __shared__ __align__(16) _Float16 sA[2][128][64], sB[2][128][64];   // 64 KB
    const int b = blockIdx.x;
    const int sb = (b & 7) * 81 + (b >> 3);
    const int bx = sb % 18, by = sb / 18;
    const int m0 = by * 128, n0 = bx * 128;
    const int tid = threadIdx.x, lane = tid & 63, wv = tid >> 6;
    const int wm = (wv >> 1) * 64, wn = (wv & 1) * 64;
    const int fr = lane & 15, fkb = (lane >> 4) * 8;

    const int srow = tid >> 3, scol = (tid & 7) * 8;   // 32 rows x 8 chunks / quarter
    const _Float16* gA = A + (size_t)(m0 + srow) * LD + scol;
    const _Float16* gB = B + (size_t)(n0 + srow) * LD + scol;

    f32x4 acc[4][4];
#pragma unroll
    for (int m = 0; m < 4; ++m)
#pragma unroll
        for (int n2 = 0; n2 < 4; ++n2) acc[m][n2] = (f32x4){0.f, 0.f, 0.f, 0.f};

    // prologue: stage kt=0 into buf 0
#pragma unroll
    for (int q = 0; q < 4; ++q) {
        gload16(&sA[0][q * 32 + srow][scol], gA + (size_t)(q * 32) * LD);
        gload16(&sB[0][q * 32 + srow][scol], gB + (size_t)(q * 32) * LD);
    }

    int cur = 0;
    for (int kt = 0; kt < 12; ++kt) {
        asm volatile("s_waitcnt vmcnt(0)" ::: "memory");  // buf[cur] DMA done (flew under prev compute)
        __syncthreads();                                  // staged + all readers of buf[cur^1] done
        if (kt + 1 < 12) {
            const int k1 = (kt + 1) * 64;
#pragma unroll
            for (int q = 0; q < 4; ++q) {
                gload16(&sA[cur ^ 1][q * 32 + srow][scol], gA + (size_t)(q * 32) * LD + k1);
                gload16(&sB[cur ^ 1][q * 32 + srow][scol], gB + (size_t)(q * 32) * LD + k1);
            }
        }

#pragma unroll
        for (int kk = 0; kk < 2; ++kk) {
            h8v fa[4], fb[4];
#pragma unroll
            for (int m = 0; m < 4; ++m) fa[m] = *(const h8v*)&sA[cur][wm + m * 16 + fr][kk * 32 + fkb];
#pragma unroll
            for (int n2 = 0; n2 < 4; ++n2) fb[n2] = *(const h8v*)&sB[cur][wn + n2 * 16 + fr][kk * 32 + fkb];
#pragma unroll
            for (int m = 0; m < 4; ++m)
#pragma unroll
                for (int n2 = 0; n2 < 4; ++n2) acc[m][n2] = MFMAH(fa[m], fb[n2], acc[m][n2]);
        }
        cur ^= 1;
    }

    const int rg = (lane >> 4) * 4;
    if (bx < 12) {
        // Q,K columns: normal row-major write into qkv
#pragma unroll
        for (int m = 0; m < 4; ++m)
#pragma unroll
            for (int n2 = 0; n2 < 4; ++n2)
#pragma unroll
                for (int r = 0; r < 4; ++r)
                    C[(size_t)(m0 + wm + m * 16 + rg + r) * LDC + (n0 + wn + n2 * 16 + fr)] =
                        (_Float16)acc[m][n2][r];
    } else {
        // V columns: write transposed into vt (token runs along r -> 8B packed)
        const int nb = m0 / 2304;                       // batch (tile never straddles)
        const int tokb = m0 - nb * 2304 + wm + rg;      // + m*16 + r
#pragma unroll
        for (int m = 0; m < 4; ++m)
#pragma unroll
            for (int n2 = 0; n2 < 4; ++n2) {
                const int f = n0 - 1536 + wn + n2 * 16 + fr;   // [0,768)
                const int head = f >> 6, e = f & 63;
                h4v v;
#pragma unroll
                for (int r = 0; r < 4; ++r) v[r] = (_Float16)acc[m][n2][r];
                *(h4v*)(vt + (size_t)((nb * 12 + head) * 64 + e) * 2304 + tokb + m * 16) = v;
            }
    }
}

// ---------------------------------------------------------------------------
// Stage 2: flash neighborhood attention, 3-wave blocks (one qx each).
// NO online softmax: scores (log2 units) exponentiated unnormalized; mask
// folded into the QK^T C-initializer. K+V in XOR-swizzled dbuf LDS,
// 1 barrier/iter, reg prefetch of kx+1, s_setprio around compute.
// O^T in registers. grid = 1152 = 8 XCDs * 144.  (r13 champion structure)
// ---------------------------------------------------------------------------
__global__ __launch_bounds__(192) void attn_flash(const _Float16* __restrict__ qkv,
                                                  const _Float16* __restrict__ vt,
                                                  _Float16* __restrict__ o,
                                                  const int* __restrict__ ksp) {
    __shared__ __align__(16) char sbuf[2][14336];   // per buf: K 6144B | V^T 8192B
    const int tid = threadIdx.x;
    const int lane = tid & 63, wv = tid >> 6;
    const int fr = lane & 15, fg = lane >> 4;

    const int b = blockIdx.x;
    const int xcd = b & 7, g = b >> 3;              // g in [0,144)
    const int qx = xcd * 6 + g / 24;
    const int hn = g % 24;
    const int head = hn >> 1, n = hn & 1;
    const int KS = *ksp;

    const int krow0 = tid >> 3, kc = tid & 7;       // K: rows krow0, krow0+24
    const int vrow0 = tid / 6,  vc = tid % 6;       // V: rows vrow0, vrow0+32
    const int ksw = (krow0 & 7) << 4;
    const int vsw = (vrow0 & 7) << 4;

    const int qy = wv * 16 + fr;
    const _Float16* qrow = qkv + (size_t)(n * 2304 + qx * 48 + qy) * 2304 + head * 64;
    h8v qa0 = *(const h8v*)(qrow + fg * 8);
    h8v qa1 = *(const h8v*)(qrow + 32 + fg * 8);
    // fold 0.125 * log2(e) into Q: scores come out in log2 units
    qa0 = qa0 * (_Float16)0.1803368801f;
    qa1 = qa1 * (_Float16)0.1803368801f;

    int nt0 = (wv * 16 - KS) >> 4;      if (nt0 < 0) nt0 = 0;
    int nt1 = (wv * 16 + 15 + KS) >> 4; if (nt1 > 2) nt1 = 2;

    // kx-invariant mask bias, folded into the QK^T accumulator init
    f32x4 mbias[3];
#pragma unroll
    for (int nt = 0; nt < 3; ++nt)
#pragma unroll
        for (int r = 0; r < 4; ++r) {
            const int dy = nt * 16 + fg * 4 + r - qy;
            mbias[nt][r] = (dy < -KS || dy > KS) ? -1e4f : 0.f;
        }

    f32x4 Oacc[4];                                  // O^T: Oacc[et][r] = O[q=fr][e=et*16+fg*4+r]
#pragma unroll
    for (int e = 0; e < 4; ++e) Oacc[e] = (f32x4){0.f, 0.f, 0.f, 0.f};
    float rs_acc = 0.f;                             // per-lane partial sum (reduced once)

    const int lo = (qx - KS) > 0 ? (qx - KS) : 0;
    const int hi = (qx + KS) < 47 ? (qx + KS) : 47;

    const _Float16* kgbase = qkv + (size_t)(n * 2304) * 2304 + 768 + head * 64;
    const _Float16* vgbase = vt + (size_t)((n * 12 + head) * 64) * 2304;

    // prologue: stage kx = lo into buf 0
    {
        const _Float16* kg = kgbase + (size_t)(lo * 48) * 2304;
        const _Float16* vg = vgbase + lo * 48;
        const s8v a0 = *(const s8v*)(kg + (size_t)krow0 * 2304 + kc * 8);
        const s8v a1 = *(const s8v*)(kg + (size_t)(krow0 + 24) * 2304 + kc * 8);
        const s8v b0 = *(const s8v*)(vg + (size_t)vrow0 * 2304 + vc * 8);
        const s8v b1 = *(const s8v*)(vg + (size_t)(vrow0 + 32) * 2304 + vc * 8);
        *(s8v*)(sbuf[0] + krow0 * 128 + ((kc * 16) ^ ksw)) = a0;
        *(s8v*)(sbuf[0] + (krow0 + 24) * 128 + ((kc * 16) ^ ksw)) = a1;
        *(s8v*)(sbuf[0] + 6144 + vrow0 * 128 + ((vc * 16) ^ vsw)) = b0;
        *(s8v*)(sbuf[0] + 6144 + (vrow0 + 32) * 128 + ((vc * 16) ^ vsw)) = b1;
    }

    int p = 0;
    for (int kx = lo; kx <= hi; ++kx) {
        __syncthreads();                            // buf[p] staged
        const bool pre = (kx < hi);
        s8v tk0, tk1, tv0, tv1;
        if (pre) {                                  // prefetch kx+1 into regs
            const _Float16* kg = kgbase + (size_t)((kx + 1) * 48) * 2304;
            const _Float16* vg = vgbase + (kx + 1) * 48;
            tk0 = *(const s8v*)(kg + (size_t)krow0 * 2304 + kc * 8);
            tk1 = *(const s8v*)(kg + (size_t)(krow0 + 24) * 2304 + kc * 8);
            tv0 = *(const s8v*)(vg + (size_t)vrow0 * 2304 + vc * 8);
            tv1 = *(const s8v*)(vg + (size_t)(vrow0 + 32) * 2304 + vc * 8);
        }

        const char* K = sbuf[p];
        const char* V = sbuf[p] + 6144;
        __builtin_amdgcn_s_setprio(1);

        // QK^T (swapped), C seeded with mask bias: s = S^T + mask (log2 units)
        f32x4 s[3];
#pragma unroll
        for (int nt = 0; nt < 3; ++nt)
            if (nt >= nt0 && nt <= nt1) {
                const int rr = nt * 16 + fr;
                const int sw = (rr & 7) << 4;
                const h8v kb0 = *(const h8v*)(K + rr * 128 + ((fg * 16) ^ sw));
                const h8v kb1 = *(const h8v*)(K + rr * 128 + ((64 + fg * 16) ^ sw));
                f32x4 z = MFMAH(kb0, qa0, mbias[nt]);
                z = MFMAH(kb1, qa1, z);
                s[nt] = z;
            }

        // unnormalized exp2 + per-lane sum + PV (O^T: mfma(V^T_frag, P_frag))
#pragma unroll
        for (int nt = 0; nt < 3; ++nt)
            if (nt >= nt0 && nt <= nt1) {
                h4v pa;
#pragma unroll
                for (int r = 0; r < 4; ++r) {
                    const float pv = exp2_fast(s[nt][r]);
                    rs_acc += pv;
                    pa[r] = (_Float16)pv;
                }
                const int slot = nt * 2 + (fg >> 1), off8 = (fg & 1) * 8;
#pragma unroll
                for (int et = 0; et < 4; ++et) {
                    const int rv = et * 16 + fr;
                    const h4v vb = *(const h4v*)(V + rv * 128 +
                                                 (((slot ^ (rv & 7)) << 4) + off8));
                    Oacc[et] = MFMAH16(vb, pa, Oacc[et]);
                }
            }
        __builtin_amdgcn_s_setprio(0);

        if (pre) {
            char* d = sbuf[p ^ 1];
            *(s8v*)(d + krow0 * 128 + ((kc * 16) ^ ksw)) = tk0;
            *(s8v*)(d + (krow0 + 24) * 128 + ((kc * 16) ^ ksw)) = tk1;
            *(s8v*)(d + 6144 + vrow0 * 128 + ((vc * 16) ^ vsw)) = tv0;
            *(s8v*)(d + 6144 + (vrow0 + 32) * 128 + ((vc * 16) ^ vsw)) = tv1;
        }
        p ^= 1;
    }

    // epilogue: single reduce of l, lane-local normalize, packed store
    rs_acc += __shfl_xor(rs_acc, 16);
    rs_acc += __shfl_xor(rs_acc, 32);
    const float linv = 1.f / rs_acc;
    _Float16* ob = o + (size_t)(n * 2304 + qx * 48 + wv * 16 + fr) * 768 + head * 64;
#pragma unroll
    for (int et = 0; et < 4; ++et) {
        h4v ov;
#pragma unroll
        for (int r = 0; r < 4; ++r) ov[r] = (_Float16)(Oacc[et][r] * linv);
        *(h4v*)(ob + et * 16 + fg * 4) = ov;
    }
}

// ---------------------------------------------------------------------------
// Stage 3: out = o @ w_out^T (fp16 in, fp32 out), BK=64, tile 128x64,
// 4 waves stacked in M (32 rows each), 432 blocks = 8*54 XCD swizzle.
// ---------------------------------------------------------------------------
__global__ __launch_bounds__(256) void gemm_out_f16(const _Float16* __restrict__ A,
                                                    const _Float16* __restrict__ B,
                                                    float* __restrict__ C) {
    constexpr int LD = 768, LDC = 768;
    __shared__ __align__(16) _Float16 sA[128][64], sB[64][64];
    const int b = blockIdx.x;
    const int sb = (b & 7) * 54 + (b >> 3);
    const int bx = sb % 12, by = sb / 12;
    const int m0 = by * 128, n0 = bx * 64;
    const int tid = threadIdx.x, lane = tid & 63, wv = tid >> 6;
    const int fr = lane & 15, fkb = (lane >> 4) * 8;

    const int srow = tid >> 3, scol = (tid & 7) * 8;   // srow in [0,32)
    const _Float16* gA = A + (size_t)(m0 + srow) * LD + scol;
    const _Float16* gB = B + (size_t)(n0 + srow) * LD + scol;

    f32x4 acc[2][4];
#pragma unroll
    for (int m = 0; m < 2; ++m)
#pragma unroll
        for (int n2 = 0; n2 < 4; ++n2) acc[m][n2] = (f32x4){0.f, 0.f, 0.f, 0.f};

    for (int kt = 0; kt < 12; ++kt) {
        const int k0 = kt * 64;
#pragma unroll
        for (int q = 0; q < 4; ++q)
            gload16(&sA[q * 32 + srow][scol], gA + (size_t)(q * 32) * LD + k0);
        gload16(&sB[srow][scol],      gB + k0);
        gload16(&sB[32 + srow][scol], gB + (size_t)32 * LD + k0);
        __syncthreads();

#pragma unroll
        for (int kk = 0; kk < 2; ++kk) {
            h8v fa[2], fb[4];
#pragma unroll
            for (int m = 0; m < 2; ++m) fa[m] = *(const h8v*)&sA[wv * 32 + m * 16 + fr][kk * 32 + fkb];
#pragma unroll
            for (int n2 = 0; n2 < 4; ++n2) fb[n2] = *(const h8v*)&sB[n2 * 16 + fr][kk * 32 + fkb];
#pragma unroll
            for (int m = 0; m < 2; ++m)
#pragma unroll
                for (int n2 = 0; n2 < 4; ++n2) acc[m][n2] = MFMAH(fa[m], fb[n2], acc[m][n2]);
        }
        __syncthreads();
    }

    const int rg = (lane >> 4) * 4;
#pragma unroll
    for (int m = 0; m < 2; ++m)
#pragma unroll
        for (int n2 = 0; n2 < 4; ++n2)
#pragma unroll
            for (int r = 0; r < 4; ++r)
                C[(size_t)(m0 + wv * 32 + m * 16 + rg + r) * LDC + (n0 + n2 * 16 + fr)] =
                    acc[m][n2][r];
}

// ---------------------------------------------------------------------------
extern "C" void kernel_launch(void* const* d_in, const int* in_sizes, int n_in,
                              void* d_out, int out_size, void* d_ws, size_t ws_size,
                              hipStream_t stream) {
    const float* x     = (const float*)d_in[0];
    const float* w_qkv = (const float*)d_in[1];
    const float* w_out = (const float*)d_in[2];
    const int*   ksp   = (const int*)d_in[3];
    float* out = (float*)d_out;

    char* ws = (char*)d_ws;
    _Float16* qkv = (_Float16*)(ws);                  // 21,233,664 B
    _Float16* vt  = (_Float16*)(ws + 21237760);       // +7,077,888 -> 28,315,648
    _Float16* o   = (_Float16*)(ws + 28315648);       // +7,077,888 -> 35,393,536
    _Float16* xh  = (_Float16*)(ws + 35393536);       // +7,077,888 -> 42,471,424
    _Float16* wqh = (_Float16*)(ws + 42471424);       // +3,538,944 -> 46,010,368
    _Float16* woh = (_Float16*)(ws + 46010368);       // +1,179,648 -> 47,190,016 total

    conv_all<<<dim3(2880), 256, 0, stream>>>(x, w_qkv, w_out, xh, wqh, woh);
    gemm_qkv_f16<<<dim3(648), 256, 0, stream>>>(xh, wqh, qkv, vt);
    attn_flash<<<dim3(1152), 192, 0, stream>>>(qkv, vt, o, ksp);
    gemm_out_f16<<<dim3(432), 256, 0, stream>>>(o, woh, out);
}

// Round 22
// 80.914 us; speedup vs baseline: 1.0983x; 1.0983x over previous
//
#include <hip/hip_runtime.h>

using f32x4 = __attribute__((ext_vector_type(4))) float;
using h8v   = __attribute__((ext_vector_type(8))) _Float16;
using h4v   = __attribute__((ext_vector_type(4))) _Float16;
using s8v   = __attribute__((ext_vector_type(8))) short;

#define MFMAH(a, b, c)   __builtin_amdgcn_mfma_f32_16x16x32_f16((a), (b), (c), 0, 0, 0)
#define MFMAH16(a, b, c) __builtin_amdgcn_mfma_f32_16x16x16f16((a), (b), (c), 0, 0, 0)

typedef __attribute__((address_space(3))) unsigned int lds_uint;
typedef const __attribute__((address_space(1))) unsigned int glb_uint;
__device__ inline void gload16(void* l, const void* g) {
    __builtin_amdgcn_global_load_lds((glb_uint*)g, (lds_uint*)l, 16, 0, 0);
}

// native 2^x (v_exp_f32); large-negative input flushes to 0
__device__ inline float exp2_fast(float x) {
    float r;
    asm("v_exp_f32 %0, %1" : "=v"(r) : "v"(x));
    return r;
}

// ---------------------------------------------------------------------------
// Fused fp32 -> fp16 conversion for x, w_qkv, w_out. 8 elems/thread.
// ---------------------------------------------------------------------------
__global__ __launch_bounds__(256) void conv_all(const float* __restrict__ x,
                                                const float* __restrict__ wq,
                                                const float* __restrict__ wo,
                                                _Float16* __restrict__ xh,
                                                _Float16* __restrict__ wqh,
                                                _Float16* __restrict__ woh) {
    const int i = blockIdx.x * blockDim.x + threadIdx.x;
    const float* src;
    _Float16* dst;
    int off;
    if (i < 442368)      { src = x;  dst = xh;  off = i; }
    else if (i < 663552) { src = wq; dst = wqh; off = i - 442368; }
    else                 { src = wo; dst = woh; off = i - 663552; }
    const float4 a = *(const float4*)(src + (size_t)off * 8);
    const float4 b = *(const float4*)(src + (size_t)off * 8 + 4);
    h8v h;
    h[0] = (_Float16)a.x; h[1] = (_Float16)a.y; h[2] = (_Float16)a.z; h[3] = (_Float16)a.w;
    h[4] = (_Float16)b.x; h[5] = (_Float16)b.y; h[6] = (_Float16)b.z; h[7] = (_Float16)b.w;
    *(h8v*)(dst + (size_t)off * 8) = h;
}

// ---------------------------------------------------------------------------
// Stage 1: qkv = x @ w_qkv^T  (fp16), BK=64 2-phase, XCD swizzle (648 = 8*81).
// Q,K columns (bx<12) -> qkv buffer; V columns (bx>=12) -> written DIRECTLY
// TRANSPOSED into vt[((n*12+head)*64+e)*2304 + token] (vtrans kernel fused).
// ---------------------------------------------------------------------------
__global__ __launch_bounds__(256) void gemm_qkv_f16(const _Float16* __restrict__ A,
                                                    const _Float16* __restrict__ B,
                                                    _Float16* __restrict__ C,
                                                    _Float16* __restrict__ vt) {
    constexpr int LD = 768, LDC = 2304;
    __shared__ __align__(16) _Float16 sA[128][64], sB[128][64];
    const int b = blockIdx.x;
    const int sb = (b & 7) * 81 + (b >> 3);
    const int bx = sb % 18, by = sb / 18;
    const int m0 = by * 128, n0 = bx * 128;
    const int tid = threadIdx.x, lane = tid & 63, wv = tid >> 6;
    const int wm = (wv >> 1) * 64, wn = (wv & 1) * 64;
    const int fr = lane & 15, fkb = (lane >> 4) * 8;

    const int srow = tid >> 3, scol = (tid & 7) * 8;   // 32 rows x 8 chunks / quarter
    const _Float16* gA = A + (size_t)(m0 + srow) * LD + scol;
    const _Float16* gB = B + (size_t)(n0 + srow) * LD + scol;

    f32x4 acc[4][4];
#pragma unroll
    for (int m = 0; m < 4; ++m)
#pragma unroll
        for (int n2 = 0; n2 < 4; ++n2) acc[m][n2] = (f32x4){0.f, 0.f, 0.f, 0.f};

    for (int kt = 0; kt < 12; ++kt) {
        const int k0 = kt * 64;
#pragma unroll
        for (int q = 0; q < 4; ++q) {
            gload16(&sA[q * 32 + srow][scol], gA + (size_t)(q * 32) * LD + k0);
            gload16(&sB[q * 32 + srow][scol], gB + (size_t)(q * 32) * LD + k0);
        }
        __syncthreads();

#pragma unroll
        for (int kk = 0; kk < 2; ++kk) {
            h8v fa[4], fb[4];
#pragma unroll
            for (int m = 0; m < 4; ++m) fa[m] = *(const h8v*)&sA[wm + m * 16 + fr][kk * 32 + fkb];
#pragma unroll
            for (int n2 = 0; n2 < 4; ++n2) fb[n2] = *(const h8v*)&sB[wn + n2 * 16 + fr][kk * 32 + fkb];
#pragma unroll
            for (int m = 0; m < 4; ++m)
#pragma unroll
                for (int n2 = 0; n2 < 4; ++n2) acc[m][n2] = MFMAH(fa[m], fb[n2], acc[m][n2]);
        }
        __syncthreads();
    }

    const int rg = (lane >> 4) * 4;
    if (bx < 12) {
        // Q,K columns: normal row-major write into qkv
#pragma unroll
        for (int m = 0; m < 4; ++m)
#pragma unroll
            for (int n2 = 0; n2 < 4; ++n2)
#pragma unroll
                for (int r = 0; r < 4; ++r)
                    C[(size_t)(m0 + wm + m * 16 + rg + r) * LDC + (n0 + wn + n2 * 16 + fr)] =
                        (_Float16)acc[m][n2][r];
    } else {
        // V columns: write transposed into vt (token runs along r -> 8B packed)
        const int nb = m0 / 2304;                       // batch (tile never straddles)
        const int tokb = m0 - nb * 2304 + wm + rg;      // + m*16 + r
#pragma unroll
        for (int m = 0; m < 4; ++m)
#pragma unroll
            for (int n2 = 0; n2 < 4; ++n2) {
                const int f = n0 - 1536 + wn + n2 * 16 + fr;   // [0,768)
                const int head = f >> 6, e = f & 63;
                h4v v;
#pragma unroll
                for (int r = 0; r < 4; ++r) v[r] = (_Float16)acc[m][n2][r];
                *(h4v*)(vt + (size_t)((nb * 12 + head) * 64 + e) * 2304 + tokb + m * 16) = v;
            }
    }
}

// ---------------------------------------------------------------------------
// Stage 2: flash neighborhood attention, 3-wave blocks (one qx each).
// NO online softmax: scores (log2 units) exponentiated unnormalized; mask
// folded into the QK^T C-initializer. K+V in XOR-swizzled dbuf LDS,
// 1 barrier/iter, reg prefetch of kx+1, s_setprio around compute.
// O^T in registers. grid = 1152 = 8 XCDs * 144.  (r13 champion structure)
// ---------------------------------------------------------------------------
__global__ __launch_bounds__(192) void attn_flash(const _Float16* __restrict__ qkv,
                                                  const _Float16* __restrict__ vt,
                                                  _Float16* __restrict__ o,
                                                  const int* __restrict__ ksp) {
    __shared__ __align__(16) char sbuf[2][14336];   // per buf: K 6144B | V^T 8192B
    const int tid = threadIdx.x;
    const int lane = tid & 63, wv = tid >> 6;
    const int fr = lane & 15, fg = lane >> 4;

    const int b = blockIdx.x;
    const int xcd = b & 7, g = b >> 3;              // g in [0,144)
    const int qx = xcd * 6 + g / 24;
    const int hn = g % 24;
    const int head = hn >> 1, n = hn & 1;
    const int KS = *ksp;

    const int krow0 = tid >> 3, kc = tid & 7;       // K: rows krow0, krow0+24
    const int vrow0 = tid / 6,  vc = tid % 6;       // V: rows vrow0, vrow0+32
    const int ksw = (krow0 & 7) << 4;
    const int vsw = (vrow0 & 7) << 4;

    const int qy = wv * 16 + fr;
    const _Float16* qrow = qkv + (size_t)(n * 2304 + qx * 48 + qy) * 2304 + head * 64;
    h8v qa0 = *(const h8v*)(qrow + fg * 8);
    h8v qa1 = *(const h8v*)(qrow + 32 + fg * 8);
    // fold 0.125 * log2(e) into Q: scores come out in log2 units
    qa0 = qa0 * (_Float16)0.1803368801f;
    qa1 = qa1 * (_Float16)0.1803368801f;

    int nt0 = (wv * 16 - KS) >> 4;      if (nt0 < 0) nt0 = 0;
    int nt1 = (wv * 16 + 15 + KS) >> 4; if (nt1 > 2) nt1 = 2;

    // kx-invariant mask bias, folded into the QK^T accumulator init
    f32x4 mbias[3];
#pragma unroll
    for (int nt = 0; nt < 3; ++nt)
#pragma unroll
        for (int r = 0; r < 4; ++r) {
            const int dy = nt * 16 + fg * 4 + r - qy;
            mbias[nt][r] = (dy < -KS || dy > KS) ? -1e4f : 0.f;
        }

    f32x4 Oacc[4];                                  // O^T: Oacc[et][r] = O[q=fr][e=et*16+fg*4+r]
#pragma unroll
    for (int e = 0; e < 4; ++e) Oacc[e] = (f32x4){0.f, 0.f, 0.f, 0.f};
    float rs_acc = 0.f;                             // per-lane partial sum (reduced once)

    const int lo = (qx - KS) > 0 ? (qx - KS) : 0;
    const int hi = (qx + KS) < 47 ? (qx + KS) : 47;

    const _Float16* kgbase = qkv + (size_t)(n * 2304) * 2304 + 768 + head * 64;
    const _Float16* vgbase = vt + (size_t)((n * 12 + head) * 64) * 2304;

    // prologue: stage kx = lo into buf 0
    {
        const _Float16* kg = kgbase + (size_t)(lo * 48) * 2304;
        const _Float16* vg = vgbase + lo * 48;
        const s8v a0 = *(const s8v*)(kg + (size_t)krow0 * 2304 + kc * 8);
        const s8v a1 = *(const s8v*)(kg + (size_t)(krow0 + 24) * 2304 + kc * 8);
        const s8v b0 = *(const s8v*)(vg + (size_t)vrow0 * 2304 + vc * 8);
        const s8v b1 = *(const s8v*)(vg + (size_t)(vrow0 + 32) * 2304 + vc * 8);
        *(s8v*)(sbuf[0] + krow0 * 128 + ((kc * 16) ^ ksw)) = a0;
        *(s8v*)(sbuf[0] + (krow0 + 24) * 128 + ((kc * 16) ^ ksw)) = a1;
        *(s8v*)(sbuf[0] + 6144 + vrow0 * 128 + ((vc * 16) ^ vsw)) = b0;
        *(s8v*)(sbuf[0] + 6144 + (vrow0 + 32) * 128 + ((vc * 16) ^ vsw)) = b1;
    }

    int p = 0;
    for (int kx = lo; kx <= hi; ++kx) {
        __syncthreads();                            // buf[p] staged
        const bool pre = (kx < hi);
        s8v tk0, tk1, tv0, tv1;
        if (pre) {                                  // prefetch kx+1 into regs
            const _Float16* kg = kgbase + (size_t)((kx + 1) * 48) * 2304;
            const _Float16* vg = vgbase + (kx + 1) * 48;
            tk0 = *(const s8v*)(kg + (size_t)krow0 * 2304 + kc * 8);
            tk1 = *(const s8v*)(kg + (size_t)(krow0 + 24) * 2304 + kc * 8);
            tv0 = *(const s8v*)(vg + (size_t)vrow0 * 2304 + vc * 8);
            tv1 = *(const s8v*)(vg + (size_t)(vrow0 + 32) * 2304 + vc * 8);
        }

        const char* K = sbuf[p];
        const char* V = sbuf[p] + 6144;
        __builtin_amdgcn_s_setprio(1);

        // QK^T (swapped), C seeded with mask bias: s = S^T + mask (log2 units)
        f32x4 s[3];
#pragma unroll
        for (int nt = 0; nt < 3; ++nt)
            if (nt >= nt0 && nt <= nt1) {
                const int rr = nt * 16 + fr;
                const int sw = (rr & 7) << 4;
                const h8v kb0 = *(const h8v*)(K + rr * 128 + ((fg * 16) ^ sw));
                const h8v kb1 = *(const h8v*)(K + rr * 128 + ((64 + fg * 16) ^ sw));
                f32x4 z = MFMAH(kb0, qa0, mbias[nt]);
                z = MFMAH(kb1, qa1, z);
                s[nt] = z;
            }

        // unnormalized exp2 + per-lane sum + PV (O^T: mfma(V^T_frag, P_frag))
#pragma unroll
        for (int nt = 0; nt < 3; ++nt)
            if (nt >= nt0 && nt <= nt1) {
                h4v pa;
#pragma unroll
                for (int r = 0; r < 4; ++r) {
                    const float pv = exp2_fast(s[nt][r]);
                    rs_acc += pv;
                    pa[r] = (_Float16)pv;
                }
                const int slot = nt * 2 + (fg >> 1), off8 = (fg & 1) * 8;
#pragma unroll
                for (int et = 0; et < 4; ++et) {
                    const int rv = et * 16 + fr;
                    const h4v vb = *(const h4v*)(V + rv * 128 +
                                                 (((slot ^ (rv & 7)) << 4) + off8));
                    Oacc[et] = MFMAH16(vb, pa, Oacc[et]);
                }
            }
        __builtin_amdgcn_s_setprio(0);

        if (pre) {
            char* d = sbuf[p ^ 1];
            *(s8v*)(d + krow0 * 128 + ((kc * 16) ^ ksw)) = tk0;
            *(s8v*)(d + (krow0 + 24) * 128 + ((kc * 16) ^ ksw)) = tk1;
            *(s8v*)(d + 6144 + vrow0 * 128 + ((vc * 16) ^ vsw)) = tv0;
            *(s8v*)(d + 6144 + (vrow0 + 32) * 128 + ((vc * 16) ^ vsw)) = tv1;
        }
        p ^= 1;
    }

    // epilogue: single reduce of l, lane-local normalize, packed store
    rs_acc += __shfl_xor(rs_acc, 16);
    rs_acc += __shfl_xor(rs_acc, 32);
    const float linv = 1.f / rs_acc;
    _Float16* ob = o + (size_t)(n * 2304 + qx * 48 + wv * 16 + fr) * 768 + head * 64;
#pragma unroll
    for (int et = 0; et < 4; ++et) {
        h4v ov;
#pragma unroll
        for (int r = 0; r < 4; ++r) ov[r] = (_Float16)(Oacc[et][r] * linv);
        *(h4v*)(ob + et * 16 + fg * 4) = ov;
    }
}

// ---------------------------------------------------------------------------
// Stage 3: out = o @ w_out^T (fp16 in, fp32 out), BK=64, tile 128x64,
// 4 waves stacked in M (32 rows each), 432 blocks = 8*54 XCD swizzle.
// ---------------------------------------------------------------------------
__global__ __launch_bounds__(256) void gemm_out_f16(const _Float16* __restrict__ A,
                                                    const _Float16* __restrict__ B,
                                                    float* __restrict__ C) {
    constexpr int LD = 768, LDC = 768;
    __shared__ __align__(16) _Float16 sA[128][64], sB[64][64];
    const int b = blockIdx.x;
    const int sb = (b & 7) * 54 + (b >> 3);
    const int bx = sb % 12, by = sb / 12;
    const int m0 = by * 128, n0 = bx * 64;
    const int tid = threadIdx.x, lane = tid & 63, wv = tid >> 6;
    const int fr = lane & 15, fkb = (lane >> 4) * 8;

    const int srow = tid >> 3, scol = (tid & 7) * 8;   // srow in [0,32)
    const _Float16* gA = A + (size_t)(m0 + srow) * LD + scol;
    const _Float16* gB = B + (size_t)(n0 + srow) * LD + scol;

    f32x4 acc[2][4];
#pragma unroll
    for (int m = 0; m < 2; ++m)
#pragma unroll
        for (int n2 = 0; n2 < 4; ++n2) acc[m][n2] = (f32x4){0.f, 0.f, 0.f, 0.f};

    for (int kt = 0; kt < 12; ++kt) {
        const int k0 = kt * 64;
#pragma unroll
        for (int q = 0; q < 4; ++q)
            gload16(&sA[q * 32 + srow][scol], gA + (size_t)(q * 32) * LD + k0);
        gload16(&sB[srow][scol],      gB + k0);
        gload16(&sB[32 + srow][scol], gB + (size_t)32 * LD + k0);
        __syncthreads();

#pragma unroll
        for (int kk = 0; kk < 2; ++kk) {
            h8v fa[2], fb[4];
#pragma unroll
            for (int m = 0; m < 2; ++m) fa[m] = *(const h8v*)&sA[wv * 32 + m * 16 + fr][kk * 32 + fkb];
#pragma unroll
            for (int n2 = 0; n2 < 4; ++n2) fb[n2] = *(const h8v*)&sB[n2 * 16 + fr][kk * 32 + fkb];
#pragma unroll
            for (int m = 0; m < 2; ++m)
#pragma unroll
                for (int n2 = 0; n2 < 4; ++n2) acc[m][n2] = MFMAH(fa[m], fb[n2], acc[m][n2]);
        }
        __syncthreads();
    }

    const int rg = (lane >> 4) * 4;
#pragma unroll
    for (int m = 0; m < 2; ++m)
#pragma unroll
        for (int n2 = 0; n2 < 4; ++n2)
#pragma unroll
            for (int r = 0; r < 4; ++r)
                C[(size_t)(m0 + wv * 32 + m * 16 + rg + r) * LDC + (n0 + n2 * 16 + fr)] =
                    acc[m][n2][r];
}

// ---------------------------------------------------------------------------
extern "C" void kernel_launch(void* const* d_in, const int* in_sizes, int n_in,
                              void* d_out, int out_size, void* d_ws, size_t ws_size,
                              hipStream_t stream) {
    const float* x     = (const float*)d_in[0];
    const float* w_qkv = (const float*)d_in[1];
    const float* w_out = (const float*)d_in[2];
    const int*   ksp   = (const int*)d_in[3];
    float* out = (float*)d_out;

    char* ws = (char*)d_ws;
    _Float16* qkv = (_Float16*)(ws);                  // 21,233,664 B
    _Float16* vt  = (_Float16*)(ws + 21237760);       // +7,077,888 -> 28,315,648
    _Float16* o   = (_Float16*)(ws + 28315648);       // +7,077,888 -> 35,393,536
    _Float16* xh  = (_Float16*)(ws + 35393536);       // +7,077,888 -> 42,471,424
    _Float16* wqh = (_Float16*)(ws + 42471424);       // +3,538,944 -> 46,010,368
    _Float16* woh = (_Float16*)(ws + 46010368);       // +1,179,648 -> 47,190,016 total

    conv_all<<<dim3(2880), 256, 0, stream>>>(x, w_qkv, w_out, xh, wqh, woh);
    gemm_qkv_f16<<<dim3(648), 256, 0, stream>>>(xh, wqh, qkv, vt);
    attn_flash<<<dim3(1152), 192, 0, stream>>>(qkv, vt, o, ksp);
    gemm_out_f16<<<dim3(432), 256, 0, stream>>>(o, woh, out);
}